// Round 2
// baseline (311.767 us; speedup 1.0000x reference)
//
#include <hip/hip_runtime.h>

#define BB 32
#define TT 128
#define II 256
#define HH 256
#define OO 128
#define FWID 512  // H + I

// Exchange: u64 slot = (stamp<<32)|float_bits(h); step s consumes stamp>=s from
// parity s&1, publishes stamp s+1 into parity (s+1)&1. Two arrays:
//   slow[2][BB][HH] : agent-scope relaxed (MALL-coherent) — proven protocol.
//   fast[2][BB][HH] : plain store (L1 write-through -> local L2) + sc0 polls
//                     (bypass L1, read shared L2). Valid only when all 8 blocks
//                     of a batch share an XCD (bk = b+32k => bk%8 == b%8, true
//                     under round-robin XCD mapping). Self-verifying: consumers
//                     time out after 800 fast polls and fall back (sticky) to
//                     the slow array. Publishers always dual-store, so either
//                     path is complete; publish remains the common overwrite
//                     gate, preserving the R8 overwrite-safety invariant.
//
// R14 (from R13: rocprof 187us matched prediction, but harness 265.8us —
// ~79us fixed gap => cooperative-launch replay overhead):
//  1) plain launch (grid 256 <= capacity 512 @ __launch_bounds__(512,2) =>
//     guaranteed co-residency; no grid.sync used).
//  2) same-XCD L2 fast exchange as above (engaged only if ws_size >= 256KB).
// Predicted: dur_us 140-190; kernel 110-140us if fast path engages;
// FETCH 12.9->~10MB; VALUBusy 43->50-60%.

typedef unsigned long long u64;
typedef float f32x2 __attribute__((ext_vector_type(2)));

__device__ __forceinline__ f32x2 mk2(float a, float b) { f32x2 r; r.x = a; r.y = b; return r; }

__device__ __forceinline__ f32x2 pk_fma(f32x2 a, f32x2 b, f32x2 c) {
    f32x2 d;
    asm("v_pk_fma_f32 %0, %1, %2, %3" : "=v"(d) : "v"(a), "v"(b), "v"(c));
    return d;
}
__device__ __forceinline__ f32x2 pk_mul(f32x2 a, f32x2 b) {
    f32x2 d;
    asm("v_pk_mul_f32 %0, %1, %2" : "=v"(d) : "v"(a), "v"(b));
    return d;
}
__device__ __forceinline__ f32x2 pk_add(f32x2 a, f32x2 b) {
    f32x2 d;
    asm("v_pk_add_f32 %0, %1, %2" : "=v"(d) : "v"(a), "v"(b));
    return d;
}

template<int CTRL>
__device__ __forceinline__ float dpp_add(float x) {
    int t = __builtin_amdgcn_update_dpp(0, __float_as_int(x), CTRL, 0xF, 0xF, true);
    return x + __int_as_float(t);
}
// 16-lane butterfly sum via DPP row_ror; result valid in all 16 lanes.
__device__ __forceinline__ float row16_sum(float x) {
    x = dpp_add<0x128>(x);  // row_ror:8
    x = dpp_add<0x124>(x);  // row_ror:4
    x = dpp_add<0x122>(x);  // row_ror:2
    x = dpp_add<0x121>(x);  // row_ror:1
    return x;
}

__device__ __forceinline__ u64 slot_ld(const u64* p) {
    return __hip_atomic_load(p, __ATOMIC_RELAXED, __HIP_MEMORY_SCOPE_AGENT);
}

// 4 contiguous u64 loads, L1-bypassing (sc0), served by the XCD-local L2.
__device__ __forceinline__ void fast_load4(const u64* p, u64& a, u64& b, u64& c, u64& d) {
    asm volatile(
        "global_load_dwordx2 %0, %4, off sc0\n\t"
        "global_load_dwordx2 %1, %4, off offset:8 sc0\n\t"
        "global_load_dwordx2 %2, %4, off offset:16 sc0\n\t"
        "global_load_dwordx2 %3, %4, off offset:24 sc0\n\t"
        "s_waitcnt vmcnt(0)"
        : "=&v"(a), "=&v"(b), "=&v"(c), "=&v"(d)
        : "v"(p)
        : "memory");
}

// One wave gathers 256 rows of one batch (4 slots/lane), stages h to LDS,
// release-stores an LDS flag. Fast (local-L2) poll with sticky fallback.
__device__ __forceinline__ void gather_to_lds(const u64* sbase, const u64* fbase,
                                              int lane, unsigned us,
                                              float* dst, int* flag, int fval,
                                              bool& fellback) {
    u64 a, b, c, d;
    bool got = false;
    if (fbase && !fellback) {
        const u64* pf = fbase + 4 * lane;
        int spins = 0;
        for (;;) {
            fast_load4(pf, a, b, c, d);
            bool ok = ((unsigned)(a >> 32) >= us) & ((unsigned)(b >> 32) >= us) &
                      ((unsigned)(c >> 32) >= us) & ((unsigned)(d >> 32) >= us);
            if (__all(ok)) { got = true; break; }
            if (++spins > 800) break;   // cross-XCD: permanently stale -> bail
        }
        if (!got) fellback = true;      // sticky: don't re-pay the timeout
    }
    if (!got) {
        const u64* p = sbase + 4 * lane;
        for (;;) {
            a = slot_ld(p);
            b = slot_ld(p + 1);
            c = slot_ld(p + 2);
            d = slot_ld(p + 3);
            bool ok = ((unsigned)(a >> 32) >= us) & ((unsigned)(b >> 32) >= us) &
                      ((unsigned)(c >> 32) >= us) & ((unsigned)(d >> 32) >= us);
            if (__all(ok)) break;
        }
    }
    float4 hv;
    hv.x = __uint_as_float((unsigned)a);
    hv.y = __uint_as_float((unsigned)b);
    hv.z = __uint_as_float((unsigned)c);
    hv.w = __uint_as_float((unsigned)d);
    *reinterpret_cast<float4*>(dst + 4 * lane) = hv;
    if (lane == 0)  // release drains the wave's ds_write before the flag
        __hip_atomic_store(flag, fval, __ATOMIC_RELEASE, __HIP_MEMORY_SCOPE_WORKGROUP);
}

__global__ __launch_bounds__(512, 2)
void stpn_kernel(const float* __restrict__ x,      // (B,T,I)
                 const float* __restrict__ wlam,   // (H,FWID)
                 const float* __restrict__ wgam,   // (H,FWID)
                 const float* __restrict__ w,      // (H,FWID)
                 const float* __restrict__ bias,   // (H)
                 const float* __restrict__ wout,   // (O,H)
                 const float* __restrict__ bout,   // (O)
                 float* __restrict__ out,          // tag(4096) | h_T(8192) | F_T
                 u64* __restrict__ slots,          // slow (agent/MALL)
                 u64* __restrict__ fasts)          // fast (XCD-local L2), may be null
{
    __shared__ __align__(16) float lh[2][HH];      // [parity][row]
    __shared__ int lflag[2];                       // [parity]

    const int tid  = threadIdx.x;
    const int bk   = blockIdx.x;
    const int b    = bk & 31;        // batch
    const int sl   = bk >> 5;        // row slice 0..7 (32 rows each)
    const int wv   = tid >> 6;       // 0..7
    const int lane = tid & 63;
    const int g    = tid >> 4;       // 16-lane group 0..31 == row-within-slice
    const int i    = tid & 15;       // lane within group
    const int r    = sl * 32 + (g & 31);

    if (tid < 2) lflag[tid] = 0;
    bool fellback = false;
    const bool have_fast = (fasts != nullptr);

    // Per-lane f-chunks of row r: f = 64*k + 4*i + c, pair j = 2k+p covers c=2p,2p+1
    // (k<4 x-part, k>=4 h-part)
    f32x2 W2[16], Lm2[16], G2[16], F2[16];
    {
        const float4* wr = reinterpret_cast<const float4*>(w    + (size_t)r * FWID);
        const float4* lr = reinterpret_cast<const float4*>(wlam + (size_t)r * FWID);
        const float4* gr = reinterpret_cast<const float4*>(wgam + (size_t)r * FWID);
#pragma unroll
        for (int k = 0; k < 8; ++k) {
            float4 t;
            t = wr[k * 16 + i]; W2[2*k]  = mk2(t.x, t.y); W2[2*k+1]  = mk2(t.z, t.w);
            t = lr[k * 16 + i]; Lm2[2*k] = mk2(t.x, t.y); Lm2[2*k+1] = mk2(t.z, t.w);
            t = gr[k * 16 + i]; G2[2*k]  = mk2(t.x, t.y); G2[2*k+1]  = mk2(t.z, t.w);
            F2[2*k] = mk2(0.f, 0.f); F2[2*k+1] = mk2(0.f, 0.f);
        }
    }
    const float bj = bias[r];
    float hl = 0.f;

    // preload x(0)
    float4 px0, px1, px2, px3;
    {
        const float4* xb4 = reinterpret_cast<const float4*>(x + (size_t)b * TT * II);
        px0 = xb4[i]; px1 = xb4[16 + i]; px2 = xb4[32 + i]; px3 = xb4[48 + i];
    }

    __syncthreads();   // lflag init visible

    for (int s = 0; s < TT; ++s) {
        const int par = s & 1;

        f32x2 X2[8];
        X2[0] = mk2(px0.x, px0.y); X2[1] = mk2(px0.z, px0.w);
        X2[2] = mk2(px1.x, px1.y); X2[3] = mk2(px1.z, px1.w);
        X2[4] = mk2(px2.x, px2.y); X2[5] = mk2(px2.z, px2.w);
        X2[6] = mk2(px3.x, px3.y); X2[7] = mk2(px3.z, px3.w);

        // ---- Phase P: independent of h(s), runs before the gather ----
        f32x2 tw2[8];                                  // h-part tw, kept for dot_h
        f32x2 dx2 = mk2(0.f, 0.f), nv2 = mk2(0.f, 0.f);
#pragma unroll
        for (int j = 0; j < 8; ++j) {                  // x-part pairs
            f32x2 t = pk_add(W2[j], F2[j]);
            dx2 = pk_fma(X2[j], t, dx2);
            nv2 = pk_fma(t, t, nv2);
        }
#pragma unroll
        for (int j = 0; j < 8; ++j) {                  // h-part pairs
            tw2[j] = pk_add(W2[8 + j], F2[8 + j]);
            nv2 = pk_fma(tw2[j], tw2[j], nv2);
        }
        float dxs = dx2.x + dx2.y;
        float nrm = nv2.x + nv2.y;
        dxs = row16_sum(dxs);
        nrm = row16_sum(nrm);
        const float invn = __builtin_amdgcn_rsqf(nrm);   // eps 1e-16 negligible, nrm = O(1)
        const f32x2 invn2 = mk2(invn, invn);
        const float dxb = dxs + bj;

        // F decay (h-independent)
#pragma unroll
        for (int j = 0; j < 16; ++j) F2[j] = pk_mul(Lm2[j], pk_mul(F2[j], invn2));

        // ---- gather (wave 0, pipelined after Phase P) ----
        if (wv == 0) {
            gather_to_lds(slots + ((size_t)par * BB + b) * HH,
                          have_fast ? fasts + ((size_t)par * BB + b) * HH : nullptr,
                          lane, (unsigned)s, lh[par], &lflag[par], s + 1, fellback);
        }

        // ---- Phase W: LDS flag spin, consume h ----
        while (__hip_atomic_load(&lflag[par], __ATOMIC_ACQUIRE, __HIP_MEMORY_SCOPE_WORKGROUP) <= s) {}
        const float4* lh4 = reinterpret_cast<const float4*>(lh[par]);
        float4 ha = lh4[i], hb = lh4[16 + i], hc = lh4[32 + i], hd = lh4[48 + i];
        f32x2 H2[8];
        H2[0] = mk2(ha.x, ha.y); H2[1] = mk2(ha.z, ha.w);
        H2[2] = mk2(hb.x, hb.y); H2[3] = mk2(hb.z, hb.w);
        H2[4] = mk2(hc.x, hc.y); H2[5] = mk2(hc.z, hc.w);
        H2[6] = mk2(hd.x, hd.y); H2[7] = mk2(hd.z, hd.w);

        // dot_h: 2 packed chains of 4 + combine (short dep depth)
        f32x2 a2 = pk_mul(H2[0], tw2[0]);
        f32x2 b2 = pk_mul(H2[1], tw2[1]);
        a2 = pk_fma(H2[2], tw2[2], a2);
        b2 = pk_fma(H2[3], tw2[3], b2);
        a2 = pk_fma(H2[4], tw2[4], a2);
        b2 = pk_fma(H2[5], tw2[5], b2);
        a2 = pk_fma(H2[6], tw2[6], a2);
        b2 = pk_fma(H2[7], tw2[7], b2);
        f32x2 c2 = pk_add(a2, b2);
        float dh = c2.x + c2.y;
        dh = row16_sum(dh);

        const float e = __expf(2.0f * (dxb + dh));
        const float h = (1.0f - 2.0f * __builtin_amdgcn_rcpf(e + 1.0f)) * invn;
        hl = h;

        // publish ASAP: fast (local L2) + slow (agent/MALL), no fences
        if (i == 0) {
            const u64 val = ((u64)(unsigned)(s + 1) << 32) | (unsigned)__float_as_uint(h);
            const size_t idx = ((size_t)(par ^ 1) * BB + b) * HH + r;
            if (have_fast) {
                u64* pf = fasts + idx;
                asm volatile("global_store_dwordx2 %0, %1, off" :: "v"(pf), "v"(val) : "memory");
            }
            __hip_atomic_store(slots + idx, val, __ATOMIC_RELAXED, __HIP_MEMORY_SCOPE_AGENT);
        }

        // x(s+1) prefetch: in flight under Phase U, consumed at next loop top
        if (s + 1 < TT) {
            const float4* xn = reinterpret_cast<const float4*>(x + ((size_t)b * TT + (s + 1)) * II);
            px0 = xn[i]; px1 = xn[16 + i]; px2 = xn[32 + i]; px3 = xn[48 + i];
        }

        // ---- Phase U: F += (gamma*input)*h ----
        const f32x2 h2v = mk2(h, h);
#pragma unroll
        for (int j = 0; j < 8; ++j)
            F2[j] = pk_fma(pk_mul(X2[j], G2[j]), h2v, F2[j]);
#pragma unroll
        for (int j = 0; j < 8; ++j)
            F2[8 + j] = pk_fma(pk_mul(G2[8 + j], H2[j]), h2v, F2[8 + j]);
    }

    // ---- epilogue: F_T, h_T ----
    {
        float4* fo = reinterpret_cast<float4*>(out + 12288 + ((size_t)b * HH + r) * FWID);
#pragma unroll
        for (int k = 0; k < 8; ++k) {
            float4 v;
            v.x = F2[2*k].x; v.y = F2[2*k].y; v.z = F2[2*k+1].x; v.w = F2[2*k+1].y;
            fo[k * 16 + i] = v;
        }
    }
    if (i == 0) out[4096 + (size_t)b * HH + r] = hl;

    // tag_space: sl==0 blocks (one per batch) gather final h (stamp TT, parity 0)
    if (sl == 0) {
        if (wv == 0) {
            gather_to_lds(slots + ((size_t)(TT & 1) * BB + b) * HH,
                          have_fast ? fasts + ((size_t)(TT & 1) * BB + b) * HH : nullptr,
                          lane, (unsigned)TT, lh[0], &lflag[0], TT + 1, fellback);
        }
        while (__hip_atomic_load(&lflag[0], __ATOMIC_ACQUIRE, __HIP_MEMORY_SCOPE_WORKGROUP) <= TT) {}
        if (tid < OO) {
            const float* hv = lh[0];
            float acc = bout[tid];
            const float* wo = wout + (size_t)tid * HH;
#pragma unroll 4
            for (int jj = 0; jj < HH; ++jj) acc = fmaf(wo[jj], hv[jj], acc);
            out[(size_t)b * OO + tid] = acc;
        }
    }
}

extern "C" void kernel_launch(void* const* d_in, const int* in_sizes, int n_in,
                              void* d_out, int out_size, void* d_ws, size_t ws_size,
                              hipStream_t stream) {
    (void)in_sizes; (void)n_in; (void)out_size;
    const float* x    = (const float*)d_in[0];
    const float* wlam = (const float*)d_in[1];
    const float* wgam = (const float*)d_in[2];
    const float* w    = (const float*)d_in[3];
    const float* bias = (const float*)d_in[4];
    const float* wout = (const float*)d_in[5];
    const float* bout = (const float*)d_in[6];
    float* out = (float*)d_out;

    const size_t SLOT_BYTES = 2ull * BB * HH * 8ull;   // 128 KB per array
    u64* slots = (u64*)d_ws;
    u64* fasts = nullptr;
    if (ws_size >= 2 * SLOT_BYTES) {
        fasts = slots + 2ull * BB * HH;                // second 128 KB
        hipMemsetAsync(d_ws, 0, 2 * SLOT_BYTES, stream);   // stamp 0 + h=0 in both
    } else {
        hipMemsetAsync(d_ws, 0, SLOT_BYTES, stream);
    }

    // Plain launch: grid 256 <= co-residency capacity 512 (launch_bounds(512,2));
    // no grid-wide sync primitive is used, so cooperative launch is unnecessary
    // and its per-replay serialization overhead (~75us observed) is avoided.
    hipLaunchKernelGGL(stpn_kernel, dim3(256), dim3(512), 0, stream,
                       x, wlam, wgam, w, bias, wout, bout, out, slots, fasts);
}

// Round 3
// 258.498 us; speedup vs baseline: 1.2061x; 1.2061x over previous
//
#include <hip/hip_runtime.h>

#define BB 32
#define TT 128
#define II 256
#define HH 256
#define OO 128
#define FWID 512  // H + I
#define FAST_TIMEOUT 128   // spins; one-time worst-case cost ~15us if fast path is dead

// Exchange: u64 slot = (stamp<<32)|float_bits(h); step s consumes stamp>=s from
// parity s&1, publishes stamp s+1 into parity (s+1)&1. Two arrays:
//   slow[2][BB][HH] : agent-scope relaxed (MALL-coherent) — proven protocol.
//   fast[2][BB][HH] : sc0 store (forced write-through to XCD-local L2) + sc0
//                     polls (L1-bypass, read local L2). Valid when all 8 blocks
//                     of a batch share an XCD (bk = b+32k => bk%8 == b%8 under
//                     round-robin mapping). Self-verifying: consumers time out
//                     after FAST_TIMEOUT fast polls and fall back (sticky) to
//                     the slow array. Publishers always dual-store; publish
//                     remains the common overwrite gate (R8 invariant intact).
//
// R15 (from R14: kernel 283us = 187 + ~93us == one-time 800-spin timeout =>
// fast path NEVER succeeded; plain store likely never reached L2. Plain launch
// itself was good: harness-rocprof gap 79->28us):
//  1) publish store now carries sc0 (glc-store pattern: write-through to L2).
//  2) FAST_TIMEOUT 800 -> 128 (bounded ~15us one-time downside).
//  3) plain launch kept.
// Predicted: fast engages -> kernel ~150us, harness ~180. Broken -> kernel
// ~202, harness ~230. Kernel ~280 would indict the plain launch instead.

typedef unsigned long long u64;
typedef float f32x2 __attribute__((ext_vector_type(2)));

__device__ __forceinline__ f32x2 mk2(float a, float b) { f32x2 r; r.x = a; r.y = b; return r; }

__device__ __forceinline__ f32x2 pk_fma(f32x2 a, f32x2 b, f32x2 c) {
    f32x2 d;
    asm("v_pk_fma_f32 %0, %1, %2, %3" : "=v"(d) : "v"(a), "v"(b), "v"(c));
    return d;
}
__device__ __forceinline__ f32x2 pk_mul(f32x2 a, f32x2 b) {
    f32x2 d;
    asm("v_pk_mul_f32 %0, %1, %2" : "=v"(d) : "v"(a), "v"(b));
    return d;
}
__device__ __forceinline__ f32x2 pk_add(f32x2 a, f32x2 b) {
    f32x2 d;
    asm("v_pk_add_f32 %0, %1, %2" : "=v"(d) : "v"(a), "v"(b));
    return d;
}

template<int CTRL>
__device__ __forceinline__ float dpp_add(float x) {
    int t = __builtin_amdgcn_update_dpp(0, __float_as_int(x), CTRL, 0xF, 0xF, true);
    return x + __int_as_float(t);
}
// 16-lane butterfly sum via DPP row_ror; result valid in all 16 lanes.
__device__ __forceinline__ float row16_sum(float x) {
    x = dpp_add<0x128>(x);  // row_ror:8
    x = dpp_add<0x124>(x);  // row_ror:4
    x = dpp_add<0x122>(x);  // row_ror:2
    x = dpp_add<0x121>(x);  // row_ror:1
    return x;
}

__device__ __forceinline__ u64 slot_ld(const u64* p) {
    return __hip_atomic_load(p, __ATOMIC_RELAXED, __HIP_MEMORY_SCOPE_AGENT);
}

// 4 contiguous u64 loads, L1-bypassing (sc0), served by the XCD-local L2.
__device__ __forceinline__ void fast_load4(const u64* p, u64& a, u64& b, u64& c, u64& d) {
    asm volatile(
        "global_load_dwordx2 %0, %4, off sc0\n\t"
        "global_load_dwordx2 %1, %4, off offset:8 sc0\n\t"
        "global_load_dwordx2 %2, %4, off offset:16 sc0\n\t"
        "global_load_dwordx2 %3, %4, off offset:24 sc0\n\t"
        "s_waitcnt vmcnt(0)"
        : "=&v"(a), "=&v"(b), "=&v"(c), "=&v"(d)
        : "v"(p)
        : "memory");
}

// One wave gathers 256 rows of one batch (4 slots/lane), stages h to LDS,
// release-stores an LDS flag. Fast (local-L2) poll with sticky fallback.
__device__ __forceinline__ void gather_to_lds(const u64* sbase, const u64* fbase,
                                              int lane, unsigned us,
                                              float* dst, int* flag, int fval,
                                              bool& fellback) {
    u64 a, b, c, d;
    bool got = false;
    if (fbase && !fellback) {
        const u64* pf = fbase + 4 * lane;
        int spins = 0;
        for (;;) {
            fast_load4(pf, a, b, c, d);
            bool ok = ((unsigned)(a >> 32) >= us) & ((unsigned)(b >> 32) >= us) &
                      ((unsigned)(c >> 32) >= us) & ((unsigned)(d >> 32) >= us);
            if (__all(ok)) { got = true; break; }
            if (++spins > FAST_TIMEOUT) break;   // dead fast path -> bail
        }
        if (!got) fellback = true;      // sticky: don't re-pay the timeout
    }
    if (!got) {
        const u64* p = sbase + 4 * lane;
        for (;;) {
            a = slot_ld(p);
            b = slot_ld(p + 1);
            c = slot_ld(p + 2);
            d = slot_ld(p + 3);
            bool ok = ((unsigned)(a >> 32) >= us) & ((unsigned)(b >> 32) >= us) &
                      ((unsigned)(c >> 32) >= us) & ((unsigned)(d >> 32) >= us);
            if (__all(ok)) break;
        }
    }
    float4 hv;
    hv.x = __uint_as_float((unsigned)a);
    hv.y = __uint_as_float((unsigned)b);
    hv.z = __uint_as_float((unsigned)c);
    hv.w = __uint_as_float((unsigned)d);
    *reinterpret_cast<float4*>(dst + 4 * lane) = hv;
    if (lane == 0)  // release drains the wave's ds_write before the flag
        __hip_atomic_store(flag, fval, __ATOMIC_RELEASE, __HIP_MEMORY_SCOPE_WORKGROUP);
}

__global__ __launch_bounds__(512, 2)
void stpn_kernel(const float* __restrict__ x,      // (B,T,I)
                 const float* __restrict__ wlam,   // (H,FWID)
                 const float* __restrict__ wgam,   // (H,FWID)
                 const float* __restrict__ w,      // (H,FWID)
                 const float* __restrict__ bias,   // (H)
                 const float* __restrict__ wout,   // (O,H)
                 const float* __restrict__ bout,   // (O)
                 float* __restrict__ out,          // tag(4096) | h_T(8192) | F_T
                 u64* __restrict__ slots,          // slow (agent/MALL)
                 u64* __restrict__ fasts)          // fast (XCD-local L2), may be null
{
    __shared__ __align__(16) float lh[2][HH];      // [parity][row]
    __shared__ int lflag[2];                       // [parity]

    const int tid  = threadIdx.x;
    const int bk   = blockIdx.x;
    const int b    = bk & 31;        // batch
    const int sl   = bk >> 5;        // row slice 0..7 (32 rows each)
    const int wv   = tid >> 6;       // 0..7
    const int lane = tid & 63;
    const int g    = tid >> 4;       // 16-lane group 0..31 == row-within-slice
    const int i    = tid & 15;       // lane within group
    const int r    = sl * 32 + (g & 31);

    if (tid < 2) lflag[tid] = 0;
    bool fellback = false;
    const bool have_fast = (fasts != nullptr);

    // Per-lane f-chunks of row r: f = 64*k + 4*i + c, pair j = 2k+p covers c=2p,2p+1
    // (k<4 x-part, k>=4 h-part)
    f32x2 W2[16], Lm2[16], G2[16], F2[16];
    {
        const float4* wr = reinterpret_cast<const float4*>(w    + (size_t)r * FWID);
        const float4* lr = reinterpret_cast<const float4*>(wlam + (size_t)r * FWID);
        const float4* gr = reinterpret_cast<const float4*>(wgam + (size_t)r * FWID);
#pragma unroll
        for (int k = 0; k < 8; ++k) {
            float4 t;
            t = wr[k * 16 + i]; W2[2*k]  = mk2(t.x, t.y); W2[2*k+1]  = mk2(t.z, t.w);
            t = lr[k * 16 + i]; Lm2[2*k] = mk2(t.x, t.y); Lm2[2*k+1] = mk2(t.z, t.w);
            t = gr[k * 16 + i]; G2[2*k]  = mk2(t.x, t.y); G2[2*k+1]  = mk2(t.z, t.w);
            F2[2*k] = mk2(0.f, 0.f); F2[2*k+1] = mk2(0.f, 0.f);
        }
    }
    const float bj = bias[r];
    float hl = 0.f;

    // preload x(0)
    float4 px0, px1, px2, px3;
    {
        const float4* xb4 = reinterpret_cast<const float4*>(x + (size_t)b * TT * II);
        px0 = xb4[i]; px1 = xb4[16 + i]; px2 = xb4[32 + i]; px3 = xb4[48 + i];
    }

    __syncthreads();   // lflag init visible

    for (int s = 0; s < TT; ++s) {
        const int par = s & 1;

        f32x2 X2[8];
        X2[0] = mk2(px0.x, px0.y); X2[1] = mk2(px0.z, px0.w);
        X2[2] = mk2(px1.x, px1.y); X2[3] = mk2(px1.z, px1.w);
        X2[4] = mk2(px2.x, px2.y); X2[5] = mk2(px2.z, px2.w);
        X2[6] = mk2(px3.x, px3.y); X2[7] = mk2(px3.z, px3.w);

        // ---- Phase P: independent of h(s), runs before the gather ----
        f32x2 tw2[8];                                  // h-part tw, kept for dot_h
        f32x2 dx2 = mk2(0.f, 0.f), nv2 = mk2(0.f, 0.f);
#pragma unroll
        for (int j = 0; j < 8; ++j) {                  // x-part pairs
            f32x2 t = pk_add(W2[j], F2[j]);
            dx2 = pk_fma(X2[j], t, dx2);
            nv2 = pk_fma(t, t, nv2);
        }
#pragma unroll
        for (int j = 0; j < 8; ++j) {                  // h-part pairs
            tw2[j] = pk_add(W2[8 + j], F2[8 + j]);
            nv2 = pk_fma(tw2[j], tw2[j], nv2);
        }
        float dxs = dx2.x + dx2.y;
        float nrm = nv2.x + nv2.y;
        dxs = row16_sum(dxs);
        nrm = row16_sum(nrm);
        const float invn = __builtin_amdgcn_rsqf(nrm);   // eps 1e-16 negligible, nrm = O(1)
        const f32x2 invn2 = mk2(invn, invn);
        const float dxb = dxs + bj;

        // F decay (h-independent)
#pragma unroll
        for (int j = 0; j < 16; ++j) F2[j] = pk_mul(Lm2[j], pk_mul(F2[j], invn2));

        // ---- gather (wave 0, pipelined after Phase P) ----
        if (wv == 0) {
            gather_to_lds(slots + ((size_t)par * BB + b) * HH,
                          have_fast ? fasts + ((size_t)par * BB + b) * HH : nullptr,
                          lane, (unsigned)s, lh[par], &lflag[par], s + 1, fellback);
        }

        // ---- Phase W: LDS flag spin, consume h ----
        while (__hip_atomic_load(&lflag[par], __ATOMIC_ACQUIRE, __HIP_MEMORY_SCOPE_WORKGROUP) <= s) {}
        const float4* lh4 = reinterpret_cast<const float4*>(lh[par]);
        float4 ha = lh4[i], hb = lh4[16 + i], hc = lh4[32 + i], hd = lh4[48 + i];
        f32x2 H2[8];
        H2[0] = mk2(ha.x, ha.y); H2[1] = mk2(ha.z, ha.w);
        H2[2] = mk2(hb.x, hb.y); H2[3] = mk2(hb.z, hb.w);
        H2[4] = mk2(hc.x, hc.y); H2[5] = mk2(hc.z, hc.w);
        H2[6] = mk2(hd.x, hd.y); H2[7] = mk2(hd.z, hd.w);

        // dot_h: 2 packed chains of 4 + combine (short dep depth)
        f32x2 a2 = pk_mul(H2[0], tw2[0]);
        f32x2 b2 = pk_mul(H2[1], tw2[1]);
        a2 = pk_fma(H2[2], tw2[2], a2);
        b2 = pk_fma(H2[3], tw2[3], b2);
        a2 = pk_fma(H2[4], tw2[4], a2);
        b2 = pk_fma(H2[5], tw2[5], b2);
        a2 = pk_fma(H2[6], tw2[6], a2);
        b2 = pk_fma(H2[7], tw2[7], b2);
        f32x2 c2 = pk_add(a2, b2);
        float dh = c2.x + c2.y;
        dh = row16_sum(dh);

        const float e = __expf(2.0f * (dxb + dh));
        const float h = (1.0f - 2.0f * __builtin_amdgcn_rcpf(e + 1.0f)) * invn;
        hl = h;

        // publish ASAP: fast (sc0 write-through -> local L2) + slow (agent/MALL)
        if (i == 0) {
            const u64 val = ((u64)(unsigned)(s + 1) << 32) | (unsigned)__float_as_uint(h);
            const size_t idx = ((size_t)(par ^ 1) * BB + b) * HH + r;
            if (have_fast) {
                u64* pf = fasts + idx;
                asm volatile("global_store_dwordx2 %0, %1, off sc0" :: "v"(pf), "v"(val) : "memory");
            }
            __hip_atomic_store(slots + idx, val, __ATOMIC_RELAXED, __HIP_MEMORY_SCOPE_AGENT);
        }

        // x(s+1) prefetch: in flight under Phase U, consumed at next loop top
        if (s + 1 < TT) {
            const float4* xn = reinterpret_cast<const float4*>(x + ((size_t)b * TT + (s + 1)) * II);
            px0 = xn[i]; px1 = xn[16 + i]; px2 = xn[32 + i]; px3 = xn[48 + i];
        }

        // ---- Phase U: F += (gamma*input)*h ----
        const f32x2 h2v = mk2(h, h);
#pragma unroll
        for (int j = 0; j < 8; ++j)
            F2[j] = pk_fma(pk_mul(X2[j], G2[j]), h2v, F2[j]);
#pragma unroll
        for (int j = 0; j < 8; ++j)
            F2[8 + j] = pk_fma(pk_mul(G2[8 + j], H2[j]), h2v, F2[8 + j]);
    }

    // ---- epilogue: F_T, h_T ----
    {
        float4* fo = reinterpret_cast<float4*>(out + 12288 + ((size_t)b * HH + r) * FWID);
#pragma unroll
        for (int k = 0; k < 8; ++k) {
            float4 v;
            v.x = F2[2*k].x; v.y = F2[2*k].y; v.z = F2[2*k+1].x; v.w = F2[2*k+1].y;
            fo[k * 16 + i] = v;
        }
    }
    if (i == 0) out[4096 + (size_t)b * HH + r] = hl;

    // tag_space: sl==0 blocks (one per batch) gather final h (stamp TT, parity 0)
    if (sl == 0) {
        if (wv == 0) {
            gather_to_lds(slots + ((size_t)(TT & 1) * BB + b) * HH,
                          have_fast ? fasts + ((size_t)(TT & 1) * BB + b) * HH : nullptr,
                          lane, (unsigned)TT, lh[0], &lflag[0], TT + 1, fellback);
        }
        while (__hip_atomic_load(&lflag[0], __ATOMIC_ACQUIRE, __HIP_MEMORY_SCOPE_WORKGROUP) <= TT) {}
        if (tid < OO) {
            const float* hv = lh[0];
            float acc = bout[tid];
            const float* wo = wout + (size_t)tid * HH;
#pragma unroll 4
            for (int jj = 0; jj < HH; ++jj) acc = fmaf(wo[jj], hv[jj], acc);
            out[(size_t)b * OO + tid] = acc;
        }
    }
}

extern "C" void kernel_launch(void* const* d_in, const int* in_sizes, int n_in,
                              void* d_out, int out_size, void* d_ws, size_t ws_size,
                              hipStream_t stream) {
    (void)in_sizes; (void)n_in; (void)out_size;
    const float* x    = (const float*)d_in[0];
    const float* wlam = (const float*)d_in[1];
    const float* wgam = (const float*)d_in[2];
    const float* w    = (const float*)d_in[3];
    const float* bias = (const float*)d_in[4];
    const float* wout = (const float*)d_in[5];
    const float* bout = (const float*)d_in[6];
    float* out = (float*)d_out;

    const size_t SLOT_BYTES = 2ull * BB * HH * 8ull;   // 128 KB per array
    u64* slots = (u64*)d_ws;
    u64* fasts = nullptr;
    if (ws_size >= 2 * SLOT_BYTES) {
        fasts = slots + 2ull * BB * HH;                // second 128 KB
        hipMemsetAsync(d_ws, 0, 2 * SLOT_BYTES, stream);   // stamp 0 + h=0 in both
    } else {
        hipMemsetAsync(d_ws, 0, SLOT_BYTES, stream);
    }

    // Plain launch: grid 256 <= co-residency capacity 512 (launch_bounds(512,2));
    // no grid-wide sync primitive is used, so cooperative launch is unnecessary.
    // R14 measured: plain launch cut the harness-rocprof gap 79us -> 28us.
    hipLaunchKernelGGL(stpn_kernel, dim3(256), dim3(512), 0, stream,
                       x, wlam, wgam, w, bias, wout, bout, out, slots, fasts);
}